// Round 1
// baseline (3811.493 us; speedup 1.0000x reference)
//
#include <hip/hip_runtime.h>
#include <math.h>

// Problem constants (fixed by setup_inputs)
#define DIMX 48      // dim
#define HID  16      // hid
#define CCH  8       // C = hid/2
#define BB   16      // batch
#define HH   256
#define WW   256
#define HWPIX (HH * WW)            // 65536
#define NPIX  (BB * HWPIX)         // 1048576
#define TH    4                    // interior rows per block
#define LCOL  (WW + 2)             // 258: col 0 and 257 are zero pads
#define LN_EPS 1e-5f

__device__ __forceinline__ float gelu_exact(float v) {
    // x * 0.5 * (1 + erf(x / sqrt(2)))
    return 0.5f * v * (1.0f + erff(v * 0.70710678118654752f));
}

// Fused: per strip of TH rows (full width), rolling 4-slot LDS window of the
// LayerNorm output n; x1 kept in a 2-row register pipeline. One barrier/row.
__global__ __launch_bounds__(256, 4) void fused_kernel(
    const float* __restrict__ x,
    const float* __restrict__ W1,     // (48,16) row-major
    const float* __restrict__ b1,     // (16)
    const float* __restrict__ gamma,  // (8)
    const float* __restrict__ beta,   // (8)
    const float* __restrict__ dw_w,   // (8,1,3,3)
    const float* __restrict__ dw_b,   // (8)
    const float* __restrict__ pw_w,   // (8,8)
    const float* __restrict__ pw_b,   // (8)
    const float* __restrict__ W2,     // (8,48)
    const float* __restrict__ b2,     // (48)
    float* __restrict__ out)          // (B,48,H,W)
{
    // n rolling buffer: [slot][channel][padded col]  (channel-major -> lane-
    // consecutive LDS addresses on both write and read => conflict-free)
    __shared__ float lnsh[4][CCH][LCOL];          // 33024 B
    __shared__ float sW1[DIMX * HID];             // 3072 B
    __shared__ float sb1[HID];
    __shared__ float sg[CCH], sbe[CCH];
    __shared__ float sdw[CCH * 9], sdwb[CCH];
    __shared__ float spw[CCH * CCH], spwb[CCH];
    __shared__ float sW2[CCH * DIMX];             // 1536 B
    __shared__ float sb2[DIMX];

    const int t = threadIdx.x;       // t = column (0..255)

    for (int i = t; i < DIMX * HID; i += 256) sW1[i] = W1[i];
    for (int i = t; i < CCH * DIMX; i += 256) sW2[i] = W2[i];
    if (t < HID) sb1[t] = b1[t];
    if (t < CCH) { sg[t] = gamma[t]; sbe[t] = beta[t]; sdwb[t] = dw_b[t]; spwb[t] = pw_b[t]; }
    if (t >= 64  && t < 64 + CCH * CCH) spw[t - 64] = pw_w[t - 64];
    if (t >= 128 && t < 128 + CCH * 9)  sdw[t - 128] = dw_w[t - 128];
    if (t >= 200 && t < 200 + DIMX)     sb2[t - 200] = b2[t - 200];
    // zero the horizontal pad columns of all 4 slots (written once, never touched again)
    if (t < 64) {
        const int slot = t >> 4, rem = t & 15;
        lnsh[slot][rem >> 1][(rem & 1) ? (LCOL - 1) : 0] = 0.0f;
    }
    __syncthreads();

    const int b  = blockIdx.x >> 6;          // 64 strips per image
    const int r0 = (blockIdx.x & 63) * TH;

    float x1_cur[CCH], x1_next[CCH];

    // stage1 for global row gr -> write n into lnsh[slot][*][1+t], x1 -> x1_next
    auto stage1 = [&](int gr, int slot) {
        if (gr < 0 || gr >= HH) {            // vertical zero pad (block-uniform branch)
#pragma unroll
            for (int c = 0; c < CCH; ++c) lnsh[slot][c][1 + t] = 0.0f;
            return;
        }
        float y[HID];
#pragma unroll
        for (int j = 0; j < HID; ++j) y[j] = sb1[j];
        const float4* __restrict__ xp =
            (const float4*)(x + ((size_t)b * HWPIX + (size_t)gr * WW + t) * DIMX);
#pragma unroll
        for (int i = 0; i < DIMX / 4; ++i) {
            const float4 v = xp[i];
            const float* w = &sW1[i * 4 * HID];
#pragma unroll
            for (int j = 0; j < HID; ++j) y[j] = fmaf(v.x, w[j], y[j]);
#pragma unroll
            for (int j = 0; j < HID; ++j) y[j] = fmaf(v.y, w[HID + j], y[j]);
#pragma unroll
            for (int j = 0; j < HID; ++j) y[j] = fmaf(v.z, w[2 * HID + j], y[j]);
#pragma unroll
            for (int j = 0; j < HID; ++j) y[j] = fmaf(v.w, w[3 * HID + j], y[j]);
        }
#pragma unroll
        for (int j = 0; j < HID; ++j) y[j] = gelu_exact(gelu_exact(y[j]));

        // layernorm over channels 8..15
        float m = 0.f;
#pragma unroll
        for (int c = 0; c < CCH; ++c) m += y[CCH + c];
        m *= 0.125f;
        float var = 0.f;
#pragma unroll
        for (int c = 0; c < CCH; ++c) { float d = y[CCH + c] - m; var = fmaf(d, d, var); }
        var *= 0.125f;
        const float rs = rsqrtf(var + LN_EPS);
#pragma unroll
        for (int c = 0; c < CCH; ++c)
            lnsh[slot][c][1 + t] = fmaf((y[CCH + c] - m) * rs, sg[c], sbe[c]);
#pragma unroll
        for (int c = 0; c < CCH; ++c) x1_next[c] = y[c];
    };

    // prologue: rows r0-1 (slot 0) and r0 (slot 1)
    stage1(r0 - 1, 0);
    stage1(r0, 1);
#pragma unroll
    for (int c = 0; c < CCH; ++c) x1_cur[c] = x1_next[c];

    for (int r = r0; r < r0 + TH; ++r) {
        // stage1 of the row below; writes slot (r - r0 + 2) & 3.
        // Safe with ONE barrier/iter: this write slot is disjoint from the slot
        // set {r-1-1.. } read by the PREVIOUS iteration's stage2, and the slot it
        // recycles (row r-2) was last read two iterations ago (>= 1 barrier ago).
        stage1(r + 1, (r - r0 + 2) & 3);
        __syncthreads();

        // ---- stage2 for row r ----
        float sp[CCH];
#pragma unroll
        for (int c = 0; c < CCH; ++c) sp[c] = sdwb[c];
        float ncv[CCH];
#pragma unroll
        for (int dr = 0; dr < 3; ++dr) {
            const int slot = (r - r0 + dr) & 3;          // rows r-1, r, r+1
            const float* lrow = &lnsh[slot][0][0];
            const int ki0 = dr * 3;
#pragma unroll
            for (int c = 0; c < CCH; ++c) {
                const float* lc = lrow + c * LCOL + t;   // cols t-1, t, t+1 (pad-shifted)
                const float nl = lc[0], nm = lc[1], nr = lc[2];
                sp[c] = fmaf(nl, sdw[c * 9 + ki0 + 0], sp[c]);
                sp[c] = fmaf(nm, sdw[c * 9 + ki0 + 1], sp[c]);
                sp[c] = fmaf(nr, sdw[c * 9 + ki0 + 2], sp[c]);
                if (dr == 1) ncv[c] = nm;
            }
        }

        // pointwise conv on center
        float chv[CCH];
#pragma unroll
        for (int co = 0; co < CCH; ++co) {
            float a = spwb[co];
#pragma unroll
            for (int ci = 0; ci < CCH; ++ci) a = fmaf(ncv[ci], spw[co * CCH + ci], a);
            chv[co] = a;
        }

        // gate with x1 (register pipeline)
        float g[CCH];
#pragma unroll
        for (int c = 0; c < CCH; ++c) g[c] = x1_cur[c] * (sp[c] * chv[c]);

        // out[d] = g @ W2 + b2, coalesced per-d stores (256B/wave/plane)
        float* obase = out + (size_t)b * DIMX * HWPIX + (size_t)r * WW + t;
#pragma unroll 8
        for (int d = 0; d < DIMX; ++d) {
            float a = sb2[d];
#pragma unroll
            for (int c = 0; c < CCH; ++c) a = fmaf(g[c], sW2[c * DIMX + d], a);
            obase[(size_t)d * HWPIX] = a;
        }

#pragma unroll
        for (int c = 0; c < CCH; ++c) x1_cur[c] = x1_next[c];
        // no trailing barrier needed (4-slot rotation proof above)
    }
}

extern "C" void kernel_launch(void* const* d_in, const int* in_sizes, int n_in,
                              void* d_out, int out_size, void* d_ws, size_t ws_size,
                              hipStream_t stream) {
    const float* x     = (const float*)d_in[0];
    const float* W1    = (const float*)d_in[1];
    const float* b1    = (const float*)d_in[2];
    const float* gamma = (const float*)d_in[3];
    const float* beta  = (const float*)d_in[4];
    const float* dw_w  = (const float*)d_in[5];
    const float* dw_b  = (const float*)d_in[6];
    const float* pw_w  = (const float*)d_in[7];
    const float* pw_b  = (const float*)d_in[8];
    const float* W2    = (const float*)d_in[9];
    const float* b2    = (const float*)d_in[10];
    float* out = (float*)d_out;

    // d_ws unused: intermediate n/x1 never leave the CU now.
    const int blocks = BB * (HH / TH);   // 1024
    fused_kernel<<<blocks, 256, 0, stream>>>(x, W1, b1, gamma, beta,
                                             dw_w, dw_b, pw_w, pw_b, W2, b2, out);
}

// Round 2
// 3353.333 us; speedup vs baseline: 1.1366x; 1.1366x over previous
//
#include <hip/hip_runtime.h>
#include <math.h>

// Problem constants (fixed by setup_inputs)
#define DIMX 48      // dim
#define HID  16      // hid
#define CCH  8       // C = hid/2
#define BB   16      // batch
#define HH   256
#define WW   256
#define HWPIX (HH * WW)            // 65536
#define TH    4                    // interior rows per block
#define LCOL  (WW + 2)             // 258: col 0 and 257 are zero pads
#define LN_EPS 1e-5f

__device__ __forceinline__ float gelu_exact(float v) {
    // x * 0.5 * (1 + erf(x / sqrt(2)))
    return 0.5f * v * (1.0f + erff(v * 0.70710678118654752f));
}

// x1 returned BY VALUE (struct) -> SROA keeps it in registers after inlining.
// (Round-1 lesson: a [&] lambda mutating captured arrays sent ALL private
// arrays to scratch: 12 GB of HBM traffic, VALUBusy 1.9%.)
struct X1v { float v[CCH]; };

__device__ __forceinline__ X1v stage1_row(
    int gr, int bimg, int t, int slot,
    const float* __restrict__ x,
    float (* __restrict__ lnsh)[CCH][LCOL],
    const float* __restrict__ sW1,
    const float* __restrict__ sb1,
    const float* __restrict__ sg,
    const float* __restrict__ sbe)
{
    X1v o;
    if (gr < 0 || gr >= HH) {          // vertical zero pad (block-uniform branch)
#pragma unroll
        for (int c = 0; c < CCH; ++c) lnsh[slot][c][1 + t] = 0.0f;
#pragma unroll
        for (int c = 0; c < CCH; ++c) o.v[c] = 0.0f;
        return o;
    }
    float y[HID];
#pragma unroll
    for (int j = 0; j < HID; ++j) y[j] = sb1[j];
    const float4* __restrict__ xp =
        (const float4*)(x + ((size_t)bimg * HWPIX + (size_t)gr * WW + t) * DIMX);
#pragma unroll
    for (int i = 0; i < DIMX / 4; ++i) {
        const float4 v = xp[i];
        const float* w = &sW1[i * 4 * HID];
#pragma unroll
        for (int j = 0; j < HID; ++j) y[j] = fmaf(v.x, w[j], y[j]);
#pragma unroll
        for (int j = 0; j < HID; ++j) y[j] = fmaf(v.y, w[HID + j], y[j]);
#pragma unroll
        for (int j = 0; j < HID; ++j) y[j] = fmaf(v.z, w[2 * HID + j], y[j]);
#pragma unroll
        for (int j = 0; j < HID; ++j) y[j] = fmaf(v.w, w[3 * HID + j], y[j]);
    }
#pragma unroll
    for (int j = 0; j < HID; ++j) y[j] = gelu_exact(gelu_exact(y[j]));

    // layernorm over channels 8..15
    float m = 0.f;
#pragma unroll
    for (int c = 0; c < CCH; ++c) m += y[CCH + c];
    m *= 0.125f;
    float var = 0.f;
#pragma unroll
    for (int c = 0; c < CCH; ++c) { float d = y[CCH + c] - m; var = fmaf(d, d, var); }
    var *= 0.125f;
    const float rs = rsqrtf(var + LN_EPS);
#pragma unroll
    for (int c = 0; c < CCH; ++c)
        lnsh[slot][c][1 + t] = fmaf((y[CCH + c] - m) * rs, sg[c], sbe[c]);
#pragma unroll
    for (int c = 0; c < CCH; ++c) o.v[c] = y[c];
    return o;
}

__global__ __launch_bounds__(256, 4) void fused_kernel(
    const float* __restrict__ x,
    const float* __restrict__ W1,     // (48,16) row-major
    const float* __restrict__ b1,     // (16)
    const float* __restrict__ gamma,  // (8)
    const float* __restrict__ beta,   // (8)
    const float* __restrict__ dw_w,   // (8,1,3,3)
    const float* __restrict__ dw_b,   // (8)
    const float* __restrict__ pw_w,   // (8,8)
    const float* __restrict__ pw_b,   // (8)
    const float* __restrict__ W2,     // (8,48)
    const float* __restrict__ b2,     // (48)
    float* __restrict__ out)          // (B,48,H,W)
{
    // n rolling buffer: [slot][channel][padded col] (lane-consecutive LDS)
    __shared__ float lnsh[4][CCH][LCOL];          // 33024 B
    __shared__ float sW1[DIMX * HID];             // 3072 B
    __shared__ float sb1[HID];
    __shared__ float sg[CCH], sbe[CCH];
    __shared__ float sdwT[9 * CCH], sdwb[CCH];    // dw transposed: [ki][c]
    __shared__ float spw[CCH * CCH], spwb[CCH];
    __shared__ float sW2t[DIMX * CCH];            // W2 transposed: [d][c]
    __shared__ float sb2[DIMX];

    const int t = threadIdx.x;       // t = column (0..255)

    for (int i = t; i < DIMX * HID; i += 256) sW1[i] = W1[i];
    for (int i = t; i < DIMX * CCH; i += 256) {
        const int d = i >> 3, c = i & 7;
        sW2t[i] = W2[c * DIMX + d];
    }
    if (t < HID) sb1[t] = b1[t];
    if (t < CCH) { sg[t] = gamma[t]; sbe[t] = beta[t]; sdwb[t] = dw_b[t]; spwb[t] = pw_b[t]; }
    if (t >= 64  && t < 64 + CCH * CCH) spw[t - 64] = pw_w[t - 64];
    if (t >= 128 && t < 128 + 9 * CCH) {
        const int ki = (t - 128) >> 3, c = (t - 128) & 7;
        sdwT[t - 128] = dw_w[c * 9 + ki];
    }
    if (t >= 200 && t < 200 + DIMX) sb2[t - 200] = b2[t - 200];
    // zero the horizontal pad columns of all 4 slots (written once)
    if (t < 64) {
        const int slot = t >> 4, rem = t & 15;
        lnsh[slot][rem >> 1][(rem & 1) ? (LCOL - 1) : 0] = 0.0f;
    }
    __syncthreads();

    const int b  = blockIdx.x >> 6;          // 64 strips per image
    const int r0 = (blockIdx.x & 63) * TH;

    // prologue: rows r0-1 (slot 0, x1 discarded) and r0 (slot 1)
    (void)stage1_row(r0 - 1, b, t, 0, x, lnsh, sW1, sb1, sg, sbe);
    X1v x1_cur = stage1_row(r0, b, t, 1, x, lnsh, sW1, sb1, sg, sbe);
    X1v x1_next;

#pragma unroll
    for (int rr = 0; rr < TH; ++rr) {
        const int r = r0 + rr;
        // stage1 of row below -> slot (rr+2)&3. Write slot is disjoint from the
        // previous iteration's read set; recycled slot was last read >=1
        // barrier ago, so ONE barrier per row is sufficient.
        x1_next = stage1_row(r + 1, b, t, (rr + 2) & 3, x, lnsh, sW1, sb1, sg, sbe);
        __syncthreads();

        // ---- stage2 for row r ----
        float sp[CCH];
#pragma unroll
        for (int c = 0; c < CCH; ++c) sp[c] = sdwb[c];
        float ncv[CCH];
#pragma unroll
        for (int dr = 0; dr < 3; ++dr) {
            const int slot = (rr + dr) & 3;          // rows r-1, r, r+1
            const int ki0 = dr * 3;
#pragma unroll
            for (int c = 0; c < CCH; ++c) {
                const float* lc = &lnsh[slot][c][t];  // cols t-1,t,t+1 (pad-shifted)
                const float nl = lc[0], nm = lc[1], nr = lc[2];
                sp[c] = fmaf(nl, sdwT[(ki0 + 0) * CCH + c], sp[c]);
                sp[c] = fmaf(nm, sdwT[(ki0 + 1) * CCH + c], sp[c]);
                sp[c] = fmaf(nr, sdwT[(ki0 + 2) * CCH + c], sp[c]);
                if (dr == 1) ncv[c] = nm;
            }
        }

        // pointwise conv on center
        float chv[CCH];
#pragma unroll
        for (int co = 0; co < CCH; ++co) {
            float a = spwb[co];
#pragma unroll
            for (int ci = 0; ci < CCH; ++ci) a = fmaf(ncv[ci], spw[co * CCH + ci], a);
            chv[co] = a;
        }

        // gate with x1 (register pipeline)
        float g[CCH];
#pragma unroll
        for (int c = 0; c < CCH; ++c) g[c] = x1_cur.v[c] * (sp[c] * chv[c]);

        // out[d] = g @ W2 + b2; W2 transposed in LDS -> 2x float4 per d
        float* obase = out + (size_t)b * DIMX * HWPIX + (size_t)r * WW + t;
        const float4* w2q = (const float4*)sW2t;
#pragma unroll 8
        for (int d = 0; d < DIMX; ++d) {
            const float4 wa = w2q[d * 2 + 0];
            const float4 wb = w2q[d * 2 + 1];
            float a = sb2[d];
            a = fmaf(g[0], wa.x, a); a = fmaf(g[1], wa.y, a);
            a = fmaf(g[2], wa.z, a); a = fmaf(g[3], wa.w, a);
            a = fmaf(g[4], wb.x, a); a = fmaf(g[5], wb.y, a);
            a = fmaf(g[6], wb.z, a); a = fmaf(g[7], wb.w, a);
            obase[(size_t)d * HWPIX] = a;
        }

#pragma unroll
        for (int c = 0; c < CCH; ++c) x1_cur.v[c] = x1_next.v[c];
        // no trailing barrier needed (4-slot rotation proof above)
    }
}

extern "C" void kernel_launch(void* const* d_in, const int* in_sizes, int n_in,
                              void* d_out, int out_size, void* d_ws, size_t ws_size,
                              hipStream_t stream) {
    const float* x     = (const float*)d_in[0];
    const float* W1    = (const float*)d_in[1];
    const float* b1    = (const float*)d_in[2];
    const float* gamma = (const float*)d_in[3];
    const float* beta  = (const float*)d_in[4];
    const float* dw_w  = (const float*)d_in[5];
    const float* dw_b  = (const float*)d_in[6];
    const float* pw_w  = (const float*)d_in[7];
    const float* pw_b  = (const float*)d_in[8];
    const float* W2    = (const float*)d_in[9];
    const float* b2    = (const float*)d_in[10];
    float* out = (float*)d_out;

    // d_ws unused: intermediates never leave the CU.
    const int blocks = BB * (HH / TH);   // 1024
    fused_kernel<<<blocks, 256, 0, stream>>>(x, W1, b1, gamma, beta,
                                             dw_w, dw_b, pw_w, pw_b, W2, b2, out);
}

// Round 3
// 1584.631 us; speedup vs baseline: 2.4053x; 2.1162x over previous
//
#include <hip/hip_runtime.h>
#include <math.h>

// Problem constants (fixed by setup_inputs)
#define DIMX 48      // dim
#define HID  16      // hid
#define CCH  8       // C = hid/2
#define BB   16      // batch
#define HH   256
#define WW   256
#define HWPIX (HH * WW)            // 65536
#define TH    4                    // interior rows per block
#define LCOL  (WW + 2)             // 258: col 0 and 257 are zero pads
#define LN_EPS 1e-5f

// Thread-private state lives in LLVM vectors (SSA values, can NEVER be
// stack-allocated) -- rounds 1-2 showed plain C arrays here get demoted to
// scratch (11 GB of HBM traffic, VALUBusy 2%, VGPR=64).
typedef float f8_t  __attribute__((ext_vector_type(8)));
typedef float f16_t __attribute__((ext_vector_type(16)));

__device__ __forceinline__ float gelu_exact(float v) {
    // x * 0.5 * (1 + erf(x / sqrt(2)))
    return 0.5f * v * (1.0f + erff(v * 0.70710678118654752f));
}

// Computes stage1 for global row gr: n -> lrow (LDS), returns x1 in a vector.
__device__ __forceinline__ f8_t stage1_row(
    int gr, int bimg, int t,
    float* __restrict__ lrow,              // &lnsh[slot][0][0]
    const float* __restrict__ x,
    const float* __restrict__ sW1,
    const float* __restrict__ sb1,
    const float* __restrict__ sg,
    const float* __restrict__ sbe)
{
    if (gr < 0 || gr >= HH) {              // vertical zero pad (block-uniform)
#pragma unroll
        for (int c = 0; c < CCH; ++c) lrow[c * LCOL + 1 + t] = 0.0f;
        return (f8_t)0.0f;
    }
    f16_t y;
#pragma unroll
    for (int j = 0; j < HID; ++j) y[j] = sb1[j];

    const float4* __restrict__ xp =
        reinterpret_cast<const float4*>(x)
        + ((size_t)bimg * HWPIX + (size_t)gr * WW + t) * (DIMX / 4);
#pragma unroll
    for (int i = 0; i < DIMX / 4; ++i) {
        const float4 v = xp[i];
        const float* w = &sW1[i * 4 * HID];
#pragma unroll
        for (int j = 0; j < HID; ++j) y[j] = fmaf(v.x, w[j], y[j]);
#pragma unroll
        for (int j = 0; j < HID; ++j) y[j] = fmaf(v.y, w[HID + j], y[j]);
#pragma unroll
        for (int j = 0; j < HID; ++j) y[j] = fmaf(v.z, w[2 * HID + j], y[j]);
#pragma unroll
        for (int j = 0; j < HID; ++j) y[j] = fmaf(v.w, w[3 * HID + j], y[j]);
    }
#pragma unroll
    for (int j = 0; j < HID; ++j) y[j] = gelu_exact(gelu_exact(y[j]));

    // layernorm over channels 8..15
    float m = 0.f;
#pragma unroll
    for (int c = 0; c < CCH; ++c) m += y[CCH + c];
    m *= 0.125f;
    float var = 0.f;
#pragma unroll
    for (int c = 0; c < CCH; ++c) { float d = y[CCH + c] - m; var = fmaf(d, d, var); }
    var *= 0.125f;
    const float rs = rsqrtf(var + LN_EPS);
#pragma unroll
    for (int c = 0; c < CCH; ++c)
        lrow[c * LCOL + 1 + t] = fmaf((y[CCH + c] - m) * rs, sg[c], sbe[c]);

    f8_t o;
#pragma unroll
    for (int c = 0; c < CCH; ++c) o[c] = y[c];
    return o;
}

__global__ __launch_bounds__(256) void fused_kernel(
    const float* __restrict__ x,
    const float* __restrict__ W1,     // (48,16) row-major
    const float* __restrict__ b1,     // (16)
    const float* __restrict__ gamma,  // (8)
    const float* __restrict__ beta,   // (8)
    const float* __restrict__ dw_w,   // (8,1,3,3)
    const float* __restrict__ dw_b,   // (8)
    const float* __restrict__ pw_w,   // (8,8)
    const float* __restrict__ pw_b,   // (8)
    const float* __restrict__ W2,     // (8,48)
    const float* __restrict__ b2,     // (48)
    float* __restrict__ out)          // (B,48,H,W)
{
    // n rolling buffer: [slot][channel][padded col] (lane-consecutive LDS)
    __shared__ float lnsh[4][CCH][LCOL];          // 33024 B
    __shared__ float sW1[DIMX * HID];             // 3072 B
    __shared__ float sb1[HID];
    __shared__ float sg[CCH], sbe[CCH];
    __shared__ float sdwT[9 * CCH], sdwb[CCH];    // dw transposed: [ki][c]
    __shared__ float spw[CCH * CCH], spwb[CCH];
    __shared__ float sW2t[DIMX * CCH];            // W2 transposed: [d][c]
    __shared__ float sb2[DIMX];

    const int t = threadIdx.x;       // t = column (0..255)

    for (int i = t; i < DIMX * HID; i += 256) sW1[i] = W1[i];
    for (int i = t; i < DIMX * CCH; i += 256) {
        const int d = i >> 3, c = i & 7;
        sW2t[i] = W2[c * DIMX + d];
    }
    if (t < HID) sb1[t] = b1[t];
    if (t < CCH) { sg[t] = gamma[t]; sbe[t] = beta[t]; sdwb[t] = dw_b[t]; spwb[t] = pw_b[t]; }
    if (t >= 64  && t < 64 + CCH * CCH) spw[t - 64] = pw_w[t - 64];
    if (t >= 128 && t < 128 + 9 * CCH) {
        const int ki = (t - 128) >> 3, c = (t - 128) & 7;
        sdwT[t - 128] = dw_w[c * 9 + ki];
    }
    if (t >= 200 && t < 200 + DIMX) sb2[t - 200] = b2[t - 200];
    // zero the horizontal pad columns of all 4 slots (written once)
    if (t < 64) {
        const int slot = t >> 4, rem = t & 15;
        lnsh[slot][rem >> 1][(rem & 1) ? (LCOL - 1) : 0] = 0.0f;
    }
    __syncthreads();

    const int b  = blockIdx.x >> 6;          // 64 strips per image
    const int r0 = (blockIdx.x & 63) * TH;

    // prologue: rows r0-1 (slot 0, x1 discarded) and r0 (slot 1)
    (void)stage1_row(r0 - 1, b, t, &lnsh[0][0][0], x, sW1, sb1, sg, sbe);
    f8_t x1_cur = stage1_row(r0, b, t, &lnsh[1][0][0], x, sW1, sb1, sg, sbe);

#pragma unroll 1   // runtime loop: keep live ranges per-row, no cross-row scheduling
    for (int rr = 0; rr < TH; ++rr) {
        const int r = r0 + rr;
        // stage1 of row below -> slot (rr+2)&3. Write slot is disjoint from
        // the previous iteration's read set; the recycled slot was last read
        // >=1 barrier ago, so ONE barrier per row is sufficient.
        f8_t x1_next = stage1_row(r + 1, b, t, &lnsh[(rr + 2) & 3][0][0],
                                  x, sW1, sb1, sg, sbe);
        __syncthreads();

        // ---- stage2 for row r ----
        f8_t sp;
#pragma unroll
        for (int c = 0; c < CCH; ++c) sp[c] = sdwb[c];
        f8_t ncv;
#pragma unroll
        for (int dr = 0; dr < 3; ++dr) {
            const float* lrow = &lnsh[(rr + dr) & 3][0][0];  // rows r-1, r, r+1
            const int ki0 = dr * 3;
#pragma unroll
            for (int c = 0; c < CCH; ++c) {
                const float* lc = lrow + c * LCOL + t;  // cols t-1,t,t+1 (pad-shifted)
                const float nl = lc[0], nm = lc[1], nr = lc[2];
                sp[c] = fmaf(nl, sdwT[(ki0 + 0) * CCH + c], sp[c]);
                sp[c] = fmaf(nm, sdwT[(ki0 + 1) * CCH + c], sp[c]);
                sp[c] = fmaf(nr, sdwT[(ki0 + 2) * CCH + c], sp[c]);
                if (dr == 1) ncv[c] = nm;
            }
        }

        // pointwise conv on center
        f8_t chv;
#pragma unroll
        for (int co = 0; co < CCH; ++co) {
            float a = spwb[co];
#pragma unroll
            for (int ci = 0; ci < CCH; ++ci) a = fmaf(ncv[ci], spw[co * CCH + ci], a);
            chv[co] = a;
        }

        // gate with x1 (register pipeline)
        f8_t g = x1_cur * (sp * chv);

        // out[d] = g @ W2 + b2; W2 transposed in LDS -> 2x float4 per d
        float* obase = out + (size_t)b * DIMX * HWPIX + (size_t)r * WW + t;
        const float4* w2q = (const float4*)sW2t;
#pragma unroll 8
        for (int d = 0; d < DIMX; ++d) {
            const float4 wa = w2q[d * 2 + 0];
            const float4 wb = w2q[d * 2 + 1];
            float a = sb2[d];
            a = fmaf(g[0], wa.x, a); a = fmaf(g[1], wa.y, a);
            a = fmaf(g[2], wa.z, a); a = fmaf(g[3], wa.w, a);
            a = fmaf(g[4], wb.x, a); a = fmaf(g[5], wb.y, a);
            a = fmaf(g[6], wb.z, a); a = fmaf(g[7], wb.w, a);
            obase[(size_t)d * HWPIX] = a;
        }

        x1_cur = x1_next;
        // no trailing barrier needed (4-slot rotation proof above)
    }
}

extern "C" void kernel_launch(void* const* d_in, const int* in_sizes, int n_in,
                              void* d_out, int out_size, void* d_ws, size_t ws_size,
                              hipStream_t stream) {
    const float* x     = (const float*)d_in[0];
    const float* W1    = (const float*)d_in[1];
    const float* b1    = (const float*)d_in[2];
    const float* gamma = (const float*)d_in[3];
    const float* beta  = (const float*)d_in[4];
    const float* dw_w  = (const float*)d_in[5];
    const float* dw_b  = (const float*)d_in[6];
    const float* pw_w  = (const float*)d_in[7];
    const float* pw_b  = (const float*)d_in[8];
    const float* W2    = (const float*)d_in[9];
    const float* b2    = (const float*)d_in[10];
    float* out = (float*)d_out;

    // d_ws unused: intermediates never leave the CU.
    const int blocks = BB * (HH / TH);   // 1024
    fused_kernel<<<blocks, 256, 0, stream>>>(x, W1, b1, gamma, beta,
                                             dw_w, dw_b, pw_w, pw_b, W2, b2, out);
}

// Round 4
// 978.444 us; speedup vs baseline: 3.8955x; 1.6195x over previous
//
#include <hip/hip_runtime.h>
#include <math.h>

// Problem constants (fixed by setup_inputs)
#define DIMX 48      // dim
#define HID  16      // hid
#define CCH  8       // C = hid/2
#define BB   16      // batch
#define HH   256
#define WW   256
#define HWPIX (HH * WW)            // 65536
#define TH    4                    // interior rows per block
#define LCOL  (WW + 2)             // 258: col 0 and 257 are zero pads
#define LN_EPS 1e-5f

// Thread-private state in LLVM vectors (SSA, never stack-allocated).
typedef float f8_t  __attribute__((ext_vector_type(8)));
typedef float f16_t __attribute__((ext_vector_type(16)));

// Scheduling cut: nothing crosses this point -> live ranges die per region.
// (Round-3 lesson: one giant region -> 256 VGPRs + 3.7 GB scratch traffic.)
#define SCHED_CUT() __builtin_amdgcn_sched_barrier(0)

__device__ __forceinline__ float gelu_exact(float v) {
    // x * 0.5 * (1 + erf(x / sqrt(2)))
    return 0.5f * v * (1.0f + erff(v * 0.70710678118654752f));
}

// y[j] += s * w[j]  -- w is a wave-uniform GLOBAL pointer with compile-time
// offsets: compiler emits s_load -> SGPR operand in v_fmac (no VGPR, no LDS).
__device__ __forceinline__ void fma16(f16_t& y, float s, const float* __restrict__ w) {
#pragma unroll
    for (int j = 0; j < HID; ++j) y[j] = fmaf(s, w[j], y[j]);
}

// stage1 for global row gr: writes n into lnsh[slot], returns x1 (registers).
__device__ __forceinline__ f8_t stage1_row(
    int gr, int bimg, int t, int slot,
    float (* __restrict__ lnsh)[CCH][LCOL],
    const float* __restrict__ x,
    const float* __restrict__ W1,
    const float* __restrict__ b1,
    const float* __restrict__ gamma,
    const float* __restrict__ beta)
{
    if (gr < 0 || gr >= HH) {              // vertical zero pad (block-uniform)
#pragma unroll
        for (int c = 0; c < CCH; ++c) lnsh[slot][c][1 + t] = 0.0f;
        return (f8_t)0.0f;
    }

    // 12 x float4 = the pixel's 48 inputs; issue all loads up-front.
    const float4* __restrict__ xp = reinterpret_cast<const float4*>(
        x + ((size_t)bimg * HWPIX + (size_t)gr * WW + t) * DIMX);
    float4 v0 = xp[0], v1 = xp[1], v2  = xp[2],  v3  = xp[3];
    float4 v4 = xp[4], v5 = xp[5], v6  = xp[6],  v7  = xp[7];
    float4 v8 = xp[8], v9 = xp[9], v10 = xp[10], v11 = xp[11];

    f16_t y;
#pragma unroll
    for (int j = 0; j < HID; ++j) y[j] = b1[j];

    // y += x @ W1; weights via scalar path. Cut every 2 k-groups (~32 SGPRs
    // of weights in flight max).
#define FB(vv, k0) \
    fma16(y, vv.x, W1 + (k0 + 0) * HID); fma16(y, vv.y, W1 + (k0 + 1) * HID); \
    fma16(y, vv.z, W1 + (k0 + 2) * HID); fma16(y, vv.w, W1 + (k0 + 3) * HID);
    FB(v0, 0)  FB(v1, 4)   SCHED_CUT();
    FB(v2, 8)  FB(v3, 12)  SCHED_CUT();
    FB(v4, 16) FB(v5, 20)  SCHED_CUT();
    FB(v6, 24) FB(v7, 28)  SCHED_CUT();
    FB(v8, 32) FB(v9, 36)  SCHED_CUT();
    FB(v10, 40) FB(v11, 44) SCHED_CUT();
#undef FB

    // double exact gelu; cut every 4 elements so only 4 erf chains are live.
#pragma unroll
    for (int j = 0; j < HID; ++j) {
        y[j] = gelu_exact(gelu_exact(y[j]));
        if ((j & 3) == 3) SCHED_CUT();
    }

    // layernorm over channels 8..15
    float m = 0.f;
#pragma unroll
    for (int c = 0; c < CCH; ++c) m += y[CCH + c];
    m *= 0.125f;
    float var = 0.f;
#pragma unroll
    for (int c = 0; c < CCH; ++c) { float d = y[CCH + c] - m; var = fmaf(d, d, var); }
    var *= 0.125f;
    const float rs = rsqrtf(var + LN_EPS);
#pragma unroll
    for (int c = 0; c < CCH; ++c)
        lnsh[slot][c][1 + t] = fmaf((y[CCH + c] - m) * rs, gamma[c], beta[c]);
    SCHED_CUT();

    f8_t o;
#pragma unroll
    for (int c = 0; c < CCH; ++c) o[c] = y[c];
    return o;
}

__global__ __launch_bounds__(256, 3) void fused_kernel(
    const float* __restrict__ x,
    const float* __restrict__ W1,     // (48,16) row-major
    const float* __restrict__ b1,     // (16)
    const float* __restrict__ gamma,  // (8)
    const float* __restrict__ beta,   // (8)
    const float* __restrict__ dw_w,   // (8,1,3,3)
    const float* __restrict__ dw_b,   // (8)
    const float* __restrict__ pw_w,   // (8,8)
    const float* __restrict__ pw_b,   // (8)
    const float* __restrict__ W2,     // (8,48)
    const float* __restrict__ b2,     // (48)
    float* __restrict__ out)          // (B,48,H,W)
{
    // ONLY LDS object: n rolling buffer [slot][channel][padded col].
    // All weights/biases read via the scalar (SGPR) path instead.
    __shared__ float lnsh[4][CCH][LCOL];          // 33024 B

    const int t = threadIdx.x;       // t = column (0..255)

    // zero the horizontal pad columns of all 4 slots (written once)
    if (t < 64) {
        const int slot = t >> 4, rem = t & 15;
        lnsh[slot][rem >> 1][(rem & 1) ? (LCOL - 1) : 0] = 0.0f;
    }
    __syncthreads();

    const int b  = blockIdx.x >> 6;          // 64 strips per image
    const int r0 = (blockIdx.x & 63) * TH;

    // prologue: rows r0-1 (slot 0, x1 discarded) and r0 (slot 1)
    (void)stage1_row(r0 - 1, b, t, 0, lnsh, x, W1, b1, gamma, beta);
    f8_t x1_cur = stage1_row(r0, b, t, 1, lnsh, x, W1, b1, gamma, beta);

#pragma unroll 1   // keep live ranges per-row; no cross-row scheduling
    for (int rr = 0; rr < TH; ++rr) {
        const int r = r0 + rr;
        // stage1 of row below -> slot (rr+2)&3. Write slot is disjoint from
        // the previous iteration's read set; the recycled slot was last read
        // >=1 barrier ago, so ONE barrier per row is sufficient.
        f8_t x1_next = stage1_row(r + 1, b, t, (rr + 2) & 3, lnsh,
                                  x, W1, b1, gamma, beta);
        __syncthreads();

        // ---- stage2 for row r ----
        f8_t sp;
#pragma unroll
        for (int c = 0; c < CCH; ++c) sp[c] = dw_b[c];
        f8_t ncv;
#pragma unroll
        for (int dr = 0; dr < 3; ++dr) {
            const float* lrow = &lnsh[(rr + dr) & 3][0][0];  // rows r-1, r, r+1
#pragma unroll
            for (int c = 0; c < CCH; ++c) {
                const float* lc = lrow + c * LCOL + t;  // cols t-1,t,t+1 (pad-shifted)
                const float nl = lc[0], nm = lc[1], nr = lc[2];
                sp[c] = fmaf(nl, dw_w[c * 9 + dr * 3 + 0], sp[c]);
                sp[c] = fmaf(nm, dw_w[c * 9 + dr * 3 + 1], sp[c]);
                sp[c] = fmaf(nr, dw_w[c * 9 + dr * 3 + 2], sp[c]);
                if (dr == 1) ncv[c] = nm;
            }
        }
        SCHED_CUT();

        // pointwise conv on center
        f8_t chv;
#pragma unroll
        for (int co = 0; co < CCH; ++co) {
            float a = pw_b[co];
#pragma unroll
            for (int ci = 0; ci < CCH; ++ci) a = fmaf(ncv[ci], pw_w[co * CCH + ci], a);
            chv[co] = a;
        }
        SCHED_CUT();

        // gate with x1 (register pipeline)
        f8_t g = x1_cur * (sp * chv);

        // out[d] = g @ W2 + b2; W2/b2 via scalar path; cut every 4 columns.
        float* obase = out + (size_t)b * DIMX * HWPIX + (size_t)r * WW + t;
#pragma unroll
        for (int d = 0; d < DIMX; ++d) {
            float a = b2[d];
#pragma unroll
            for (int c = 0; c < CCH; ++c) a = fmaf(g[c], W2[c * DIMX + d], a);
            obase[(size_t)d * HWPIX] = a;
            if ((d & 3) == 3) SCHED_CUT();
        }

        x1_cur = x1_next;
        // no trailing barrier needed (4-slot rotation proof above)
    }
}

extern "C" void kernel_launch(void* const* d_in, const int* in_sizes, int n_in,
                              void* d_out, int out_size, void* d_ws, size_t ws_size,
                              hipStream_t stream) {
    const float* x     = (const float*)d_in[0];
    const float* W1    = (const float*)d_in[1];
    const float* b1    = (const float*)d_in[2];
    const float* gamma = (const float*)d_in[3];
    const float* beta  = (const float*)d_in[4];
    const float* dw_w  = (const float*)d_in[5];
    const float* dw_b  = (const float*)d_in[6];
    const float* pw_w  = (const float*)d_in[7];
    const float* pw_b  = (const float*)d_in[8];
    const float* W2    = (const float*)d_in[9];
    const float* b2    = (const float*)d_in[10];
    float* out = (float*)d_out;

    // d_ws unused: intermediates never leave the CU.
    const int blocks = BB * (HH / TH);   // 1024
    fused_kernel<<<blocks, 256, 0, stream>>>(x, W1, b1, gamma, beta,
                                             dw_w, dw_b, pw_w, pw_b, W2, b2, out);
}

// Round 5
// 564.791 us; speedup vs baseline: 6.7485x; 1.7324x over previous
//
#include <hip/hip_runtime.h>
#include <math.h>

// Problem constants (fixed by setup_inputs)
#define DIMX 48      // dim
#define HID  16      // hid
#define CCH  8       // C = hid/2
#define BB   16      // batch
#define HH   256
#define WW   256
#define HWPIX (HH * WW)            // 65536
#define TH    4                    // interior rows per block
#define LCOL  (WW + 2)             // 258: col 0 and 257 are zero pads
#define LN_EPS 1e-5f

// Thread-private state in LLVM vectors (SSA, never stack-allocated).
typedef float f8_t  __attribute__((ext_vector_type(8)));
typedef float f16_t __attribute__((ext_vector_type(16)));

// Scheduling cut: live ranges die per region (anti-spill, proven round 3->4).
#define SCHED_CUT() __builtin_amdgcn_sched_barrier(0)

// erf via Abramowitz-Stegun 7.1.26 (max abs err 1.5e-7 -- well under the
// 2.4e-4 fp32-reordering noise already accepted by the harness).
// ~12 VALU incl. one v_rcp_f32 + one v_exp_f32, vs ~60+ for libm erff.
__device__ __forceinline__ float erf_fast(float z) {
    const float az = fabsf(z);
    const float t  = __builtin_amdgcn_rcpf(fmaf(0.3275911f, az, 1.0f));
    float p = fmaf(1.061405429f, t, -1.453152027f);
    p = fmaf(p, t, 1.421413741f);
    p = fmaf(p, t, -0.284496736f);
    p = fmaf(p, t, 0.254829592f);
    p = p * t;
    const float e = __expf(-z * z);
    const float r = fmaf(-p, e, 1.0f);      // erf(|z|)
    return copysignf(r, z);
}

__device__ __forceinline__ float gelu_exact(float v) {
    // 0.5 * v * (1 + erf(v/sqrt(2)))
    const float er = erf_fast(v * 0.70710678118654752f);
    return v * fmaf(0.5f, er, 0.5f);
}

// y[j] += s * w[j]  -- w is a wave-uniform GLOBAL pointer with compile-time
// offsets: compiler emits s_load -> SGPR operand in v_fmac (no VGPR, no LDS).
__device__ __forceinline__ void fma16(f16_t& y, float s, const float* __restrict__ w) {
#pragma unroll
    for (int j = 0; j < HID; ++j) y[j] = fmaf(s, w[j], y[j]);
}

// stage1 for global row gr: writes n into lnsh[slot], returns x1 (registers).
__device__ __forceinline__ f8_t stage1_row(
    int gr, int bimg, int t, int slot,
    float (* __restrict__ lnsh)[CCH][LCOL],
    const float* __restrict__ x,
    const float* __restrict__ W1,
    const float* __restrict__ b1,
    const float* __restrict__ gamma,
    const float* __restrict__ beta)
{
    if (gr < 0 || gr >= HH) {              // vertical zero pad (block-uniform)
#pragma unroll
        for (int c = 0; c < CCH; ++c) lnsh[slot][c][1 + t] = 0.0f;
        return (f8_t)0.0f;
    }

    // 12 x float4 = the pixel's 48 inputs; issue all loads up-front.
    const float4* __restrict__ xp = reinterpret_cast<const float4*>(
        x + ((size_t)bimg * HWPIX + (size_t)gr * WW + t) * DIMX);
    float4 v0 = xp[0], v1 = xp[1], v2  = xp[2],  v3  = xp[3];
    float4 v4 = xp[4], v5 = xp[5], v6  = xp[6],  v7  = xp[7];
    float4 v8 = xp[8], v9 = xp[9], v10 = xp[10], v11 = xp[11];

    f16_t y;
#pragma unroll
    for (int j = 0; j < HID; ++j) y[j] = b1[j];

    // y += x @ W1; weights via scalar path. One 4-k-row block (64 weights =
    // 64 SGPRs of s_load results) per scheduling region.
#define FB(vv, k0) \
    fma16(y, vv.x, W1 + (k0 + 0) * HID); fma16(y, vv.y, W1 + (k0 + 1) * HID); \
    fma16(y, vv.z, W1 + (k0 + 2) * HID); fma16(y, vv.w, W1 + (k0 + 3) * HID); \
    SCHED_CUT();
    FB(v0, 0)  FB(v1, 4)  FB(v2, 8)   FB(v3, 12)
    FB(v4, 16) FB(v5, 20) FB(v6, 24)  FB(v7, 28)
    FB(v8, 32) FB(v9, 36) FB(v10, 40) FB(v11, 44)
#undef FB

    // double gelu (cheap poly erf); cut every 8 elements.
#pragma unroll
    for (int j = 0; j < HID; ++j) {
        y[j] = gelu_exact(gelu_exact(y[j]));
        if ((j & 7) == 7) SCHED_CUT();
    }

    // layernorm over channels 8..15
    float m = 0.f;
#pragma unroll
    for (int c = 0; c < CCH; ++c) m += y[CCH + c];
    m *= 0.125f;
    float var = 0.f;
#pragma unroll
    for (int c = 0; c < CCH; ++c) { float d = y[CCH + c] - m; var = fmaf(d, d, var); }
    var *= 0.125f;
    const float rs = rsqrtf(var + LN_EPS);
#pragma unroll
    for (int c = 0; c < CCH; ++c)
        lnsh[slot][c][1 + t] = fmaf((y[CCH + c] - m) * rs, gamma[c], beta[c]);
    SCHED_CUT();

    f8_t o;
#pragma unroll
    for (int c = 0; c < CCH; ++c) o[c] = y[c];
    return o;
}

__global__ __launch_bounds__(256, 3) void fused_kernel(
    const float* __restrict__ x,
    const float* __restrict__ W1,     // (48,16) row-major
    const float* __restrict__ b1,     // (16)
    const float* __restrict__ gamma,  // (8)
    const float* __restrict__ beta,   // (8)
    const float* __restrict__ dw_w,   // (8,1,3,3)
    const float* __restrict__ dw_b,   // (8)
    const float* __restrict__ pw_w,   // (8,8)
    const float* __restrict__ pw_b,   // (8)
    const float* __restrict__ W2,     // (8,48)
    const float* __restrict__ b2,     // (48)
    float* __restrict__ out)          // (B,48,H,W)
{
    // ONLY LDS object: n rolling buffer [slot][channel][padded col].
    // All weights/biases read via the scalar (SGPR) path instead.
    __shared__ float lnsh[4][CCH][LCOL];          // 33024 B

    const int t = threadIdx.x;       // t = column (0..255)

    // zero the horizontal pad columns of all 4 slots (written once)
    if (t < 64) {
        const int slot = t >> 4, rem = t & 15;
        lnsh[slot][rem >> 1][(rem & 1) ? (LCOL - 1) : 0] = 0.0f;
    }
    __syncthreads();

    const int b  = blockIdx.x >> 6;          // 64 strips per image
    const int r0 = (blockIdx.x & 63) * TH;

    // prologue: rows r0-1 (slot 0, x1 discarded) and r0 (slot 1)
    (void)stage1_row(r0 - 1, b, t, 0, lnsh, x, W1, b1, gamma, beta);
    f8_t x1_cur = stage1_row(r0, b, t, 1, lnsh, x, W1, b1, gamma, beta);

#pragma unroll 1   // keep live ranges per-row; no cross-row scheduling
    for (int rr = 0; rr < TH; ++rr) {
        const int r = r0 + rr;
        // stage1 of row below -> slot (rr+2)&3. Write slot is disjoint from
        // the previous iteration's read set; the recycled slot was last read
        // >=1 barrier ago, so ONE barrier per row is sufficient.
        f8_t x1_next = stage1_row(r + 1, b, t, (rr + 2) & 3, lnsh,
                                  x, W1, b1, gamma, beta);
        __syncthreads();

        // ---- stage2 for row r ----
        f8_t sp;
#pragma unroll
        for (int c = 0; c < CCH; ++c) sp[c] = dw_b[c];
        f8_t ncv;
#pragma unroll
        for (int dr = 0; dr < 3; ++dr) {
            const float* lrow = &lnsh[(rr + dr) & 3][0][0];  // rows r-1, r, r+1
#pragma unroll
            for (int c = 0; c < CCH; ++c) {
                const float* lc = lrow + c * LCOL + t;  // cols t-1,t,t+1 (pad-shifted)
                const float nl = lc[0], nm = lc[1], nr = lc[2];
                sp[c] = fmaf(nl, dw_w[c * 9 + dr * 3 + 0], sp[c]);
                sp[c] = fmaf(nm, dw_w[c * 9 + dr * 3 + 1], sp[c]);
                sp[c] = fmaf(nr, dw_w[c * 9 + dr * 3 + 2], sp[c]);
                if (dr == 1) ncv[c] = nm;
            }
        }
        SCHED_CUT();

        // pointwise conv on center
        f8_t chv;
#pragma unroll
        for (int co = 0; co < CCH; ++co) {
            float a = pw_b[co];
#pragma unroll
            for (int ci = 0; ci < CCH; ++ci) a = fmaf(ncv[ci], pw_w[co * CCH + ci], a);
            chv[co] = a;
        }
        SCHED_CUT();

        // gate with x1 (register pipeline)
        f8_t g = x1_cur * (sp * chv);

        // out[d] = g @ W2 + b2; W2/b2 via scalar path; cut every 4 columns.
        float* obase = out + (size_t)b * DIMX * HWPIX + (size_t)r * WW + t;
#pragma unroll
        for (int d = 0; d < DIMX; ++d) {
            float a = b2[d];
#pragma unroll
            for (int c = 0; c < CCH; ++c) a = fmaf(g[c], W2[c * DIMX + d], a);
            obase[(size_t)d * HWPIX] = a;
            if ((d & 3) == 3) SCHED_CUT();
        }

        x1_cur = x1_next;
        // no trailing barrier needed (4-slot rotation proof above)
    }
}

extern "C" void kernel_launch(void* const* d_in, const int* in_sizes, int n_in,
                              void* d_out, int out_size, void* d_ws, size_t ws_size,
                              hipStream_t stream) {
    const float* x     = (const float*)d_in[0];
    const float* W1    = (const float*)d_in[1];
    const float* b1    = (const float*)d_in[2];
    const float* gamma = (const float*)d_in[3];
    const float* beta  = (const float*)d_in[4];
    const float* dw_w  = (const float*)d_in[5];
    const float* dw_b  = (const float*)d_in[6];
    const float* pw_w  = (const float*)d_in[7];
    const float* pw_b  = (const float*)d_in[8];
    const float* W2    = (const float*)d_in[9];
    const float* b2    = (const float*)d_in[10];
    float* out = (float*)d_out;

    // d_ws unused: intermediates never leave the CU.
    const int blocks = BB * (HH / TH);   // 1024
    fused_kernel<<<blocks, 256, 0, stream>>>(x, W1, b1, gamma, beta,
                                             dw_w, dw_b, pw_w, pw_b, W2, b2, out);
}